// Round 1
// baseline (76.497 us; speedup 1.0000x reference)
//
#include <hip/hip_runtime.h>

#define SQ3F 1.7320508075688772f
#define SQ5F 2.2360679774997896f

// m=2 basis matrices (exact transcription of _m2_basis; s = sqrt(3)/2)
__device__ const float M2B[5][3][3] = {
  {{0.f, 0.f, 0.8660254037844386f}, {0.f, 0.f, 0.f}, {0.8660254037844386f, 0.f, 0.f}},
  {{0.f, 0.8660254037844386f, 0.f}, {0.8660254037844386f, 0.f, 0.f}, {0.f, 0.f, 0.f}},
  {{-0.5f, 0.f, 0.f}, {0.f, 1.0f, 0.f}, {0.f, 0.f, -0.5f}},
  {{0.f, 0.f, 0.f}, {0.f, 0.f, 0.8660254037844386f}, {0.f, 0.8660254037844386f, 0.f}},
  {{-0.8660254037844386f, 0.f, 0.f}, {0.f, 0.f, 0.f}, {0.f, 0.f, 0.8660254037844386f}}
};

// ---------------- Phase 1: per-block mask counts ----------------
__global__ void count_kernel(const float2* __restrict__ x, int N, int rounds,
                             int* __restrict__ counts) {
  const int t = threadIdx.x;
  const int base = blockIdx.x * rounds * 256;
  int cf = 0, ct = 0;
  for (int r = 0; r < rounds; ++r) {
    int i = base + r * 256 + t;
    if (i < N) {
      float2 v = x[i];
      cf += (v.x > 0.5f) ? 1 : 0;
      ct += (v.y > 0.5f) ? 1 : 0;
    }
  }
  for (int o = 32; o; o >>= 1) { cf += __shfl_down(cf, o); ct += __shfl_down(ct, o); }
  __shared__ int sF[4], sT[4];
  const int lane = t & 63, wave = t >> 6;
  if (lane == 0) { sF[wave] = cf; sT[wave] = ct; }
  __syncthreads();
  if (t == 0) {
    counts[2 * blockIdx.x]     = sF[0] + sF[1] + sF[2] + sF[3];
    counts[2 * blockIdx.x + 1] = sT[0] + sT[1] + sT[2] + sT[3];
  }
}

// ---------------- Phase 2: exclusive scan over block counts (1 block) -------
__global__ void scan_kernel(const int* __restrict__ counts, int nblocks,
                            int* __restrict__ offsets) {
  __shared__ int sf[1024], st[1024];
  const int t = threadIdx.x;
  sf[t] = (t < nblocks) ? counts[2 * t]     : 0;
  st[t] = (t < nblocks) ? counts[2 * t + 1] : 0;
  __syncthreads();
  for (int d = 1; d < 1024; d <<= 1) {
    int vf = 0, vt = 0;
    if (t >= d) { vf = sf[t - d]; vt = st[t - d]; }
    __syncthreads();
    sf[t] += vf; st[t] += vt;
    __syncthreads();
  }
  if (t < nblocks) {
    offsets[2 * t]     = (t > 0) ? sf[t - 1] : 0;
    offsets[2 * t + 1] = (t > 0) ? st[t - 1] : 0;
  }
}

// ---------------- Phase 3: stable compaction of indices ----------------
__global__ void scatter_kernel(const float2* __restrict__ x, int N, int E, int rounds,
                               const int* __restrict__ offsets,
                               int* __restrict__ from_idx, int* __restrict__ to_idx) {
  const int t = threadIdx.x;
  const int lane = t & 63, wave = t >> 6;
  const int base = blockIdx.x * rounds * 256;
  __shared__ int wcF[4], wcT[4];
  int baseF = offsets[2 * blockIdx.x];
  int baseT = offsets[2 * blockIdx.x + 1];
  for (int r = 0; r < rounds; ++r) {
    int i = base + r * 256 + t;
    bool mf = false, mt = false;
    if (i < N) {
      float2 v = x[i];
      mf = (v.x > 0.5f);
      mt = (v.y > 0.5f);
    }
    unsigned long long bf = __ballot(mf);
    unsigned long long bt = __ballot(mt);
    if (lane == 0) { wcF[wave] = __popcll(bf); wcT[wave] = __popcll(bt); }
    __syncthreads();
    int woF = 0, woT = 0;
    for (int w = 0; w < wave; ++w) { woF += wcF[w]; woT += wcT[w]; }
    const int totF = wcF[0] + wcF[1] + wcF[2] + wcF[3];
    const int totT = wcT[0] + wcT[1] + wcT[2] + wcT[3];
    unsigned long long lm = (1ull << lane) - 1ull;
    if (mf) {
      int rk = baseF + woF + (int)__popcll(bf & lm);
      if (rk < E) from_idx[rk] = i;
    }
    if (mt) {
      int rk = baseT + woT + (int)__popcll(bt & lm);
      if (rk < E) to_idx[rk] = i;
    }
    __syncthreads();
    baseF += totF; baseT += totT;
  }
}

// ---------------- Phase 4: edge loop -> 18 sufficient statistics -----------
__global__ void edge_reduce_kernel(const float* __restrict__ pos,
                                   const float2* __restrict__ x,
                                   const int* __restrict__ from_idx,
                                   const int* __restrict__ to_idx,
                                   int E, float* __restrict__ accum) {
  float s[18];
#pragma unroll
  for (int j = 0; j < 18; ++j) s[j] = 0.f;
  const int stride = gridDim.x * blockDim.x;
  for (int k = blockIdx.x * blockDim.x + threadIdx.x; k < E; k += stride) {
    int f  = from_idx[k];
    int tt = to_idx[k];
    float ex = pos[3 * tt]     - pos[3 * f];
    float ey = pos[3 * tt + 1] - pos[3 * f + 1];
    float ez = pos[3 * tt + 2] - pos[3 * f + 2];
    float2 nf = x[tt];
    float x2 = ex * ex, y2 = ey * ey, z2 = ez * ez;
    float sh1x = SQ3F * ex, sh1y = SQ3F * ey, sh1z = SQ3F * ez;
    float sh20 = SQ5F * (SQ3F * ex * ez);
    float sh21 = SQ5F * (SQ3F * ex * ey);
    float sh22 = SQ5F * (y2 - 0.5f * (x2 + z2));
    float sh23 = SQ5F * (SQ3F * ey * ez);
    float sh24 = SQ5F * (0.5f * SQ3F * (z2 - x2));
    s[0] += nf.x;  s[1] += nf.y;
    s[2] += nf.x * sh1x;  s[3] += nf.x * sh1y;  s[4] += nf.x * sh1z;
    s[5] += nf.y * sh1x;  s[6] += nf.y * sh1y;  s[7] += nf.y * sh1z;
    s[8]  += nf.x * sh20; s[9]  += nf.x * sh21; s[10] += nf.x * sh22;
    s[11] += nf.x * sh23; s[12] += nf.x * sh24;
    s[13] += nf.y * sh20; s[14] += nf.y * sh21; s[15] += nf.y * sh22;
    s[16] += nf.y * sh23; s[17] += nf.y * sh24;
  }
#pragma unroll
  for (int j = 0; j < 18; ++j)
    for (int o = 32; o; o >>= 1) s[j] += __shfl_down(s[j], o);
  __shared__ float ls[4][18];
  const int lane = threadIdx.x & 63, wave = threadIdx.x >> 6;
  if (lane == 0) {
#pragma unroll
    for (int j = 0; j < 18; ++j) ls[wave][j] = s[j];
  }
  __syncthreads();
  if (threadIdx.x < 18) {
    float v = ls[0][threadIdx.x] + ls[1][threadIdx.x] + ls[2][threadIdx.x] + ls[3][threadIdx.x];
    atomicAdd(&accum[threadIdx.x], v);
  }
}

// ---------------- Phase 5: tiny epilogue (1 block) ----------------
__global__ void finalize_kernel(const float* __restrict__ accum,
                                const float* __restrict__ w0,   // tp1_w0 (2,64)
                                const float* __restrict__ w1,   // tp1_w1 (2,24)
                                const float* __restrict__ w2,   // tp1_w2 (2,16)
                                const float* __restrict__ w_0e2e, // (64,16)
                                const float* __restrict__ w_2e0e, // (16,64)
                                const float* __restrict__ w_1o1o, // (24,24)
                                const float* __restrict__ w_2e2e, // (16,16)
                                float* __restrict__ out) {
  const int t = threadIdx.x;
  __shared__ float g0[64], g1[24][3], g2[16][5];
  __shared__ float a16[16], b16[16], T1[24][3], T2[16][5];
  __shared__ float A1[3][3], A2[5][5];
  __shared__ float W112s[45], W222s[125];
  __shared__ float rn112, rn222;
  const float inv = 0.28867513459481287f; // 1/sqrt(12)

  // --- g tensors from the 18 sums; zero W112 ---
  if (t < 64) g0[t] = inv * (accum[0] * w0[t] + accum[1] * w0[64 + t]);
  if (t >= 64 && t < 136) {
    int i = t - 64; int w = i / 3, j = i % 3;
    g1[w][j] = inv * (accum[2 + j] * w1[w] + accum[5 + j] * w1[24 + w]);
  }
  if (t >= 136 && t < 216) {
    int i = t - 136; int w = i / 5, j = i % 5;
    g2[w][j] = inv * (accum[8 + j] * w2[w] + accum[13 + j] * w2[16 + w]);
  }
  if (t >= 216 && t < 256 && (t - 216) < 45) W112s[t - 216] = 0.f;
  if (t < 5) W112s[40 + t] = 0.f;
  __syncthreads();

  // --- build W112 (unnormalized), W222 via m=2 basis ---
  if (t == 0) {
    const float s = 0.8660254037844386f;
    W112s[(0 * 3 + 2) * 5 + 0] = s;  W112s[(2 * 3 + 0) * 5 + 0] = s;
    W112s[(0 * 3 + 1) * 5 + 1] = s;  W112s[(1 * 3 + 0) * 5 + 1] = s;
    W112s[(1 * 3 + 1) * 5 + 2] = 1.0f;
    W112s[(0 * 3 + 0) * 5 + 2] = -0.5f;
    W112s[(2 * 3 + 2) * 5 + 2] = -0.5f;
    W112s[(1 * 3 + 2) * 5 + 3] = s;  W112s[(2 * 3 + 1) * 5 + 3] = s;
    W112s[(2 * 3 + 2) * 5 + 4] = s;
    W112s[(0 * 3 + 0) * 5 + 4] = -s;
  }
  if (t >= 32 && t < 57) {
    int idx = t - 32; int i = idx / 5, j = idx % 5;
    float P[3][3];
    for (int a = 0; a < 3; ++a)
      for (int b = 0; b < 3; ++b) {
        float sacc = 0.f;
        for (int cc = 0; cc < 3; ++cc)
          sacc += M2B[i][a][cc] * M2B[j][cc][b] + M2B[j][a][cc] * M2B[i][cc][b];
        P[a][b] = 0.5f * sacc;
      }
    float tr3 = (P[0][0] + P[1][1] + P[2][2]) * (1.0f / 3.0f);
    P[0][0] -= tr3; P[1][1] -= tr3; P[2][2] -= tr3;
    for (int k = 0; k < 5; ++k) {
      float sacc = 0.f;
      for (int a = 0; a < 3; ++a)
        for (int b = 0; b < 3; ++b) sacc += P[a][b] * M2B[k][b][a];
      W222s[(i * 5 + j) * 5 + k] = sacc * (1.0f / 1.5f);
    }
  }
  __syncthreads();
  if (t == 0) { float ss = 0.f; for (int i = 0; i < 45; ++i)  ss += W112s[i] * W112s[i]; rn112 = rsqrtf(ss); }
  if (t == 1) { float ss = 0.f; for (int i = 0; i < 125; ++i) ss += W222s[i] * W222s[i]; rn222 = rsqrtf(ss); }
  __syncthreads();
  if (t < 45) W112s[t] *= rn112;
  if (t >= 45 && t < 170) W222s[t - 45] *= rn222;
  __syncthreads();

  // --- contractions ---
  if (t < 16) { float s = 0.f; for (int u = 0; u < 64; ++u) s += w_0e2e[u * 16 + t] * g0[u]; a16[t] = s; }
  if (t >= 16 && t < 32) { int u = t - 16; float s = 0.f; for (int v = 0; v < 64; ++v) s += w_2e0e[u * 64 + v] * g0[v]; b16[u] = s; }
  if (t >= 32 && t < 104) { int i = t - 32; int u = i / 3, j = i % 3; float s = 0.f; for (int v = 0; v < 24; ++v) s += w_1o1o[u * 24 + v] * g1[v][j]; T1[u][j] = s; }
  if (t >= 104 && t < 184) { int i = t - 104; int u = i / 5, j = i % 5; float s = 0.f; for (int v = 0; v < 16; ++v) s += w_2e2e[u * 16 + v] * g2[v][j]; T2[u][j] = s; }
  __syncthreads();
  if (t < 9) { int i = t / 3, j = t % 3; float s = 0.f; for (int u = 0; u < 24; ++u) s += g1[u][i] * T1[u][j]; A1[i][j] = s; }
  if (t >= 9 && t < 34) { int i2 = t - 9; int i = i2 / 5, j = i2 % 5; float s = 0.f; for (int u = 0; u < 16; ++u) s += g2[u][i] * T2[u][j]; A2[i][j] = s; }
  __syncthreads();
  if (t < 5) {
    const float inv_s5 = 0.4472135954999579f;
    const float c = sqrtf(5.0f / 5248.0f);
    float s12 = 0.f;
    for (int v = 0; v < 16; ++v) s12 += (a16[v] + b16[v]) * g2[v][t];
    float s3 = 0.f;
    for (int i = 0; i < 3; ++i)
      for (int j = 0; j < 3; ++j) s3 += A1[i][j] * W112s[(i * 3 + j) * 5 + t];
    float s4 = 0.f;
    for (int i = 0; i < 5; ++i)
      for (int j = 0; j < 5; ++j) s4 += A2[i][j] * W222s[(i * 5 + j) * 5 + t];
    out[t] = c * (inv_s5 * s12 + s3 + s4);
  }
}

extern "C" void kernel_launch(void* const* d_in, const int* in_sizes, int n_in,
                              void* d_out, int out_size, void* d_ws, size_t ws_size,
                              hipStream_t stream) {
  const float2* x   = (const float2*)d_in[0];
  const float*  pos = (const float*)d_in[1];
  const float*  tp1_w0 = (const float*)d_in[2];
  const float*  tp1_w1 = (const float*)d_in[3];
  const float*  tp1_w2 = (const float*)d_in[4];
  const float*  w_0e2e = (const float*)d_in[5];
  const float*  w_2e0e = (const float*)d_in[6];
  const float*  w_1o1o = (const float*)d_in[7];
  const float*  w_2e2e = (const float*)d_in[8];

  const int N = in_sizes[0] / 2;
  const int E = N / 2;

  // choose rounds so that nblocks <= 1024 (single-block scan)
  int rounds = 16;
  int ipb = 256 * rounds;
  int nblocks = (N + ipb - 1) / ipb;
  while (nblocks > 1024) { rounds <<= 1; ipb = 256 * rounds; nblocks = (N + ipb - 1) / ipb; }

  // ws layout: [accum 18f pad->128B][counts 8KB][offsets 8KB][from_idx E][to_idx E]
  char* ws = (char*)d_ws;
  float* accum   = (float*)ws;
  int* counts    = (int*)(ws + 128);
  int* offsets   = (int*)(ws + 128 + 8192);
  int* from_idx  = (int*)(ws + 128 + 16384);
  int* to_idx    = from_idx + E;

  hipMemsetAsync(accum, 0, 18 * sizeof(float), stream);
  hipMemsetAsync(from_idx, 0, (size_t)2 * E * sizeof(int), stream); // nonzero pad fill_value=0

  count_kernel<<<nblocks, 256, 0, stream>>>(x, N, rounds, counts);
  scan_kernel<<<1, 1024, 0, stream>>>(counts, nblocks, offsets);
  scatter_kernel<<<nblocks, 256, 0, stream>>>(x, N, E, rounds, offsets, from_idx, to_idx);
  edge_reduce_kernel<<<2048, 256, 0, stream>>>(pos, x, from_idx, to_idx, E, accum);
  finalize_kernel<<<1, 256, 0, stream>>>(accum, tp1_w0, tp1_w1, tp1_w2,
                                         w_0e2e, w_2e0e, w_1o1o, w_2e2e, (float*)d_out);
}

// Round 2
// 66.078 us; speedup vs baseline: 1.1577x; 1.1577x over previous
//
#include <hip/hip_runtime.h>

#define SQ3F 1.7320508075688772f
#define SQ5F 2.2360679774997896f

// m=2 basis matrices (exact transcription of _m2_basis; s = sqrt(3)/2)
__device__ const float M2B[5][3][3] = {
  {{0.f, 0.f, 0.8660254037844386f}, {0.f, 0.f, 0.f}, {0.8660254037844386f, 0.f, 0.f}},
  {{0.f, 0.8660254037844386f, 0.f}, {0.8660254037844386f, 0.f, 0.f}, {0.f, 0.f, 0.f}},
  {{-0.5f, 0.f, 0.f}, {0.f, 1.0f, 0.f}, {0.f, 0.f, -0.5f}},
  {{0.f, 0.f, 0.f}, {0.f, 0.f, 0.8660254037844386f}, {0.f, 0.8660254037844386f, 0.f}},
  {{-0.8660254037844386f, 0.f, 0.f}, {0.f, 0.f, 0.f}, {0.f, 0.f, 0.8660254037844386f}}
};

// ---------------- Phase 1: per-block mask counts + zero-fill index arrays ---
__global__ void count_kernel(const float2* __restrict__ x, int N, int rounds,
                             int* __restrict__ counts,
                             int4* __restrict__ zero_base, int nzero4) {
  const int t = threadIdx.x;
  const int base = blockIdx.x * rounds * 256;
  // grid-stride zero-fill of from_idx/to_idx (2E contiguous ints) with int4
  const int gstride = gridDim.x * 256;
  const int4 z4 = make_int4(0, 0, 0, 0);
  for (int i = blockIdx.x * 256 + t; i < nzero4; i += gstride) zero_base[i] = z4;

  int cf = 0, ct = 0;
  for (int r = 0; r < rounds; ++r) {
    int i = base + r * 256 + t;
    if (i < N) {
      float2 v = x[i];
      cf += (v.x > 0.5f) ? 1 : 0;
      ct += (v.y > 0.5f) ? 1 : 0;
    }
  }
  for (int o = 32; o; o >>= 1) { cf += __shfl_down(cf, o); ct += __shfl_down(ct, o); }
  __shared__ int sF[4], sT[4];
  const int lane = t & 63, wave = t >> 6;
  if (lane == 0) { sF[wave] = cf; sT[wave] = ct; }
  __syncthreads();
  if (t == 0) {
    counts[2 * blockIdx.x]     = sF[0] + sF[1] + sF[2] + sF[3];
    counts[2 * blockIdx.x + 1] = sT[0] + sT[1] + sT[2] + sT[3];
  }
}

// ---------------- Phase 2: exclusive scan over block counts (1 block) -------
// Also zeroes the 18-float accumulator (runs before edge_reduce).
__global__ void scan_kernel(const int* __restrict__ counts, int nblocks,
                            int* __restrict__ offsets, float* __restrict__ accum) {
  __shared__ int sf[1024], st[1024];
  const int t = threadIdx.x;
  if (t < 18) accum[t] = 0.f;
  sf[t] = (t < nblocks) ? counts[2 * t]     : 0;
  st[t] = (t < nblocks) ? counts[2 * t + 1] : 0;
  __syncthreads();
  for (int d = 1; d < 1024; d <<= 1) {
    int vf = 0, vt = 0;
    if (t >= d) { vf = sf[t - d]; vt = st[t - d]; }
    __syncthreads();
    sf[t] += vf; st[t] += vt;
    __syncthreads();
  }
  if (t < nblocks) {
    offsets[2 * t]     = (t > 0) ? sf[t - 1] : 0;
    offsets[2 * t + 1] = (t > 0) ? st[t - 1] : 0;
  }
}

// ---------------- Phase 3: stable compaction of indices ----------------
__global__ void scatter_kernel(const float2* __restrict__ x, int N, int E, int rounds,
                               const int* __restrict__ offsets,
                               int* __restrict__ from_idx, int* __restrict__ to_idx) {
  const int t = threadIdx.x;
  const int lane = t & 63, wave = t >> 6;
  const int base = blockIdx.x * rounds * 256;
  __shared__ int wcF[4], wcT[4];
  int baseF = offsets[2 * blockIdx.x];
  int baseT = offsets[2 * blockIdx.x + 1];
  for (int r = 0; r < rounds; ++r) {
    int i = base + r * 256 + t;
    bool mf = false, mt = false;
    if (i < N) {
      float2 v = x[i];
      mf = (v.x > 0.5f);
      mt = (v.y > 0.5f);
    }
    unsigned long long bf = __ballot(mf);
    unsigned long long bt = __ballot(mt);
    if (lane == 0) { wcF[wave] = __popcll(bf); wcT[wave] = __popcll(bt); }
    __syncthreads();
    int woF = 0, woT = 0;
    for (int w = 0; w < wave; ++w) { woF += wcF[w]; woT += wcT[w]; }
    const int totF = wcF[0] + wcF[1] + wcF[2] + wcF[3];
    const int totT = wcT[0] + wcT[1] + wcT[2] + wcT[3];
    unsigned long long lm = (1ull << lane) - 1ull;
    if (mf) {
      int rk = baseF + woF + (int)__popcll(bf & lm);
      if (rk < E) from_idx[rk] = i;
    }
    if (mt) {
      int rk = baseT + woT + (int)__popcll(bt & lm);
      if (rk < E) to_idx[rk] = i;
    }
    __syncthreads();
    baseF += totF; baseT += totT;
  }
}

// ---------------- Phase 4: edge loop -> 18 sufficient statistics -----------
__global__ void edge_reduce_kernel(const float* __restrict__ pos,
                                   const float2* __restrict__ x,
                                   const int* __restrict__ from_idx,
                                   const int* __restrict__ to_idx,
                                   int E, float* __restrict__ accum) {
  float s[18];
#pragma unroll
  for (int j = 0; j < 18; ++j) s[j] = 0.f;
  const int stride = gridDim.x * blockDim.x;
  for (int k = blockIdx.x * blockDim.x + threadIdx.x; k < E; k += stride) {
    int f  = from_idx[k];
    int tt = to_idx[k];
    float ex = pos[3 * tt]     - pos[3 * f];
    float ey = pos[3 * tt + 1] - pos[3 * f + 1];
    float ez = pos[3 * tt + 2] - pos[3 * f + 2];
    float2 nf = x[tt];
    float x2 = ex * ex, y2 = ey * ey, z2 = ez * ez;
    float sh1x = SQ3F * ex, sh1y = SQ3F * ey, sh1z = SQ3F * ez;
    float sh20 = SQ5F * (SQ3F * ex * ez);
    float sh21 = SQ5F * (SQ3F * ex * ey);
    float sh22 = SQ5F * (y2 - 0.5f * (x2 + z2));
    float sh23 = SQ5F * (SQ3F * ey * ez);
    float sh24 = SQ5F * (0.5f * SQ3F * (z2 - x2));
    s[0] += nf.x;  s[1] += nf.y;
    s[2] += nf.x * sh1x;  s[3] += nf.x * sh1y;  s[4] += nf.x * sh1z;
    s[5] += nf.y * sh1x;  s[6] += nf.y * sh1y;  s[7] += nf.y * sh1z;
    s[8]  += nf.x * sh20; s[9]  += nf.x * sh21; s[10] += nf.x * sh22;
    s[11] += nf.x * sh23; s[12] += nf.x * sh24;
    s[13] += nf.y * sh20; s[14] += nf.y * sh21; s[15] += nf.y * sh22;
    s[16] += nf.y * sh23; s[17] += nf.y * sh24;
  }
#pragma unroll
  for (int j = 0; j < 18; ++j)
    for (int o = 32; o; o >>= 1) s[j] += __shfl_down(s[j], o);
  __shared__ float ls[4][18];
  const int lane = threadIdx.x & 63, wave = threadIdx.x >> 6;
  if (lane == 0) {
#pragma unroll
    for (int j = 0; j < 18; ++j) ls[wave][j] = s[j];
  }
  __syncthreads();
  if (threadIdx.x < 18) {
    float v = ls[0][threadIdx.x] + ls[1][threadIdx.x] + ls[2][threadIdx.x] + ls[3][threadIdx.x];
    atomicAdd(&accum[threadIdx.x], v);
  }
}

// ---------------- Phase 5: tiny epilogue (1 block) ----------------
__global__ void finalize_kernel(const float* __restrict__ accum,
                                const float* __restrict__ w0,   // tp1_w0 (2,64)
                                const float* __restrict__ w1,   // tp1_w1 (2,24)
                                const float* __restrict__ w2,   // tp1_w2 (2,16)
                                const float* __restrict__ w_0e2e, // (64,16)
                                const float* __restrict__ w_2e0e, // (16,64)
                                const float* __restrict__ w_1o1o, // (24,24)
                                const float* __restrict__ w_2e2e, // (16,16)
                                float* __restrict__ out) {
  const int t = threadIdx.x;
  __shared__ float g0[64], g1[24][3], g2[16][5];
  __shared__ float a16[16], b16[16], T1[24][3], T2[16][5];
  __shared__ float A1[3][3], A2[5][5];
  __shared__ float W112s[45], W222s[125];
  __shared__ float rn112, rn222;
  const float inv = 0.28867513459481287f; // 1/sqrt(12)

  // --- g tensors from the 18 sums; zero W112 ---
  if (t < 64) g0[t] = inv * (accum[0] * w0[t] + accum[1] * w0[64 + t]);
  if (t >= 64 && t < 136) {
    int i = t - 64; int w = i / 3, j = i % 3;
    g1[w][j] = inv * (accum[2 + j] * w1[w] + accum[5 + j] * w1[24 + w]);
  }
  if (t >= 136 && t < 216) {
    int i = t - 136; int w = i / 5, j = i % 5;
    g2[w][j] = inv * (accum[8 + j] * w2[w] + accum[13 + j] * w2[16 + w]);
  }
  if (t >= 216 && t < 256 && (t - 216) < 45) W112s[t - 216] = 0.f;
  if (t < 5) W112s[40 + t] = 0.f;
  __syncthreads();

  // --- build W112 (unnormalized), W222 via m=2 basis ---
  if (t == 0) {
    const float s = 0.8660254037844386f;
    W112s[(0 * 3 + 2) * 5 + 0] = s;  W112s[(2 * 3 + 0) * 5 + 0] = s;
    W112s[(0 * 3 + 1) * 5 + 1] = s;  W112s[(1 * 3 + 0) * 5 + 1] = s;
    W112s[(1 * 3 + 1) * 5 + 2] = 1.0f;
    W112s[(0 * 3 + 0) * 5 + 2] = -0.5f;
    W112s[(2 * 3 + 2) * 5 + 2] = -0.5f;
    W112s[(1 * 3 + 2) * 5 + 3] = s;  W112s[(2 * 3 + 1) * 5 + 3] = s;
    W112s[(2 * 3 + 2) * 5 + 4] = s;
    W112s[(0 * 3 + 0) * 5 + 4] = -s;
  }
  if (t >= 32 && t < 57) {
    int idx = t - 32; int i = idx / 5, j = idx % 5;
    float P[3][3];
    for (int a = 0; a < 3; ++a)
      for (int b = 0; b < 3; ++b) {
        float sacc = 0.f;
        for (int cc = 0; cc < 3; ++cc)
          sacc += M2B[i][a][cc] * M2B[j][cc][b] + M2B[j][a][cc] * M2B[i][cc][b];
        P[a][b] = 0.5f * sacc;
      }
    float tr3 = (P[0][0] + P[1][1] + P[2][2]) * (1.0f / 3.0f);
    P[0][0] -= tr3; P[1][1] -= tr3; P[2][2] -= tr3;
    for (int k = 0; k < 5; ++k) {
      float sacc = 0.f;
      for (int a = 0; a < 3; ++a)
        for (int b = 0; b < 3; ++b) sacc += P[a][b] * M2B[k][b][a];
      W222s[(i * 5 + j) * 5 + k] = sacc * (1.0f / 1.5f);
    }
  }
  __syncthreads();
  if (t == 0) { float ss = 0.f; for (int i = 0; i < 45; ++i)  ss += W112s[i] * W112s[i]; rn112 = rsqrtf(ss); }
  if (t == 1) { float ss = 0.f; for (int i = 0; i < 125; ++i) ss += W222s[i] * W222s[i]; rn222 = rsqrtf(ss); }
  __syncthreads();
  if (t < 45) W112s[t] *= rn112;
  if (t >= 45 && t < 170) W222s[t - 45] *= rn222;
  __syncthreads();

  // --- contractions ---
  if (t < 16) { float s = 0.f; for (int u = 0; u < 64; ++u) s += w_0e2e[u * 16 + t] * g0[u]; a16[t] = s; }
  if (t >= 16 && t < 32) { int u = t - 16; float s = 0.f; for (int v = 0; v < 64; ++v) s += w_2e0e[u * 64 + v] * g0[v]; b16[u] = s; }
  if (t >= 32 && t < 104) { int i = t - 32; int u = i / 3, j = i % 3; float s = 0.f; for (int v = 0; v < 24; ++v) s += w_1o1o[u * 24 + v] * g1[v][j]; T1[u][j] = s; }
  if (t >= 104 && t < 184) { int i = t - 104; int u = i / 5, j = i % 5; float s = 0.f; for (int v = 0; v < 16; ++v) s += w_2e2e[u * 16 + v] * g2[v][j]; T2[u][j] = s; }
  __syncthreads();
  if (t < 9) { int i = t / 3, j = t % 3; float s = 0.f; for (int u = 0; u < 24; ++u) s += g1[u][i] * T1[u][j]; A1[i][j] = s; }
  if (t >= 9 && t < 34) { int i2 = t - 9; int i = i2 / 5, j = i2 % 5; float s = 0.f; for (int u = 0; u < 16; ++u) s += g2[u][i] * T2[u][j]; A2[i][j] = s; }
  __syncthreads();
  if (t < 5) {
    const float inv_s5 = 0.4472135954999579f;
    const float c = sqrtf(5.0f / 5248.0f);
    float s12 = 0.f;
    for (int v = 0; v < 16; ++v) s12 += (a16[v] + b16[v]) * g2[v][t];
    float s3 = 0.f;
    for (int i = 0; i < 3; ++i)
      for (int j = 0; j < 3; ++j) s3 += A1[i][j] * W112s[(i * 3 + j) * 5 + t];
    float s4 = 0.f;
    for (int i = 0; i < 5; ++i)
      for (int j = 0; j < 5; ++j) s4 += A2[i][j] * W222s[(i * 5 + j) * 5 + t];
    out[t] = c * (inv_s5 * s12 + s3 + s4);
  }
}

extern "C" void kernel_launch(void* const* d_in, const int* in_sizes, int n_in,
                              void* d_out, int out_size, void* d_ws, size_t ws_size,
                              hipStream_t stream) {
  const float2* x   = (const float2*)d_in[0];
  const float*  pos = (const float*)d_in[1];
  const float*  tp1_w0 = (const float*)d_in[2];
  const float*  tp1_w1 = (const float*)d_in[3];
  const float*  tp1_w2 = (const float*)d_in[4];
  const float*  w_0e2e = (const float*)d_in[5];
  const float*  w_2e0e = (const float*)d_in[6];
  const float*  w_1o1o = (const float*)d_in[7];
  const float*  w_2e2e = (const float*)d_in[8];

  const int N = in_sizes[0] / 2;
  const int E = N / 2;

  // choose rounds so that nblocks <= 1024 (single-block scan)
  int rounds = 16;
  int ipb = 256 * rounds;
  int nblocks = (N + ipb - 1) / ipb;
  while (nblocks > 1024) { rounds <<= 1; ipb = 256 * rounds; nblocks = (N + ipb - 1) / ipb; }

  // ws layout: [accum 18f pad->128B][counts 8KB][offsets 8KB][from_idx E][to_idx E]
  char* ws = (char*)d_ws;
  float* accum   = (float*)ws;
  int* counts    = (int*)(ws + 128);
  int* offsets   = (int*)(ws + 128 + 8192);
  int* from_idx  = (int*)(ws + 128 + 16384);
  int* to_idx    = from_idx + E;

  // from_idx/to_idx are contiguous: zero 2E ints via int4 inside count_kernel
  const int nzero4 = (2 * E) / 4;   // E is a multiple of 2; 2E % 4 == 0 for our N

  count_kernel<<<nblocks, 256, 0, stream>>>(x, N, rounds, counts, (int4*)from_idx, nzero4);
  scan_kernel<<<1, 1024, 0, stream>>>(counts, nblocks, offsets, accum);
  scatter_kernel<<<nblocks, 256, 0, stream>>>(x, N, E, rounds, offsets, from_idx, to_idx);
  edge_reduce_kernel<<<2048, 256, 0, stream>>>(pos, x, from_idx, to_idx, E, accum);
  finalize_kernel<<<1, 256, 0, stream>>>(accum, tp1_w0, tp1_w1, tp1_w2,
                                         w_0e2e, w_2e0e, w_1o1o, w_2e2e, (float*)d_out);
}